// Round 1
// baseline (189.802 us; speedup 1.0000x reference)
//
#include <hip/hip_runtime.h>
#include <hip/hip_bf16.h>
#include <stdint.h>

// B=2, S=2048, D=1024, H=16, DH=64. Causal self-attention block, bf16 MFMA pipeline.

typedef __attribute__((ext_vector_type(8))) short bf16x8;   // 8 bf16 = 16B (A/B frag)
typedef __attribute__((ext_vector_type(4))) float f32x4;    // C/D frag

typedef const __attribute__((address_space(1))) uint32_t* gp1_t;
typedef __attribute__((address_space(3))) uint32_t* lp3_t;

static __device__ __forceinline__ uint16_t f2b(float x) {
  __hip_bfloat16 h = __float2bfloat16(x);
  return *reinterpret_cast<uint16_t*>(&h);
}
static __device__ __forceinline__ uint32_t pk2(float a, float b) {
  return (uint32_t)f2b(a) | ((uint32_t)f2b(b) << 16);
}

// Stage R rows x 64 bf16 (128B = 8 chunks of 16B) tile into LDS.
// LDS dest is linear (global_load_lds requirement); XOR swizzle (chunk ^= row&7)
// applied by pre-swizzling the per-lane GLOBAL source address (m173 pattern).
template <int ISSUES>
static __device__ __forceinline__ void stage64(const uint16_t* __restrict__ g, int gstride,
                                               uint8_t* lds, int t) {
#pragma unroll
  for (int i = 0; i < ISSUES; ++i) {
    int p = i * 256 + t;          // 16B-chunk index
    int row = p >> 3, c = p & 7;
    const uint16_t* src = g + row * gstride + ((c ^ (row & 7)) << 3);
    __builtin_amdgcn_global_load_lds((gp1_t)src, (lp3_t)(lds + (p & ~63) * 16), 16, 0, 0);
  }
}

// Read a 16B fragment from a swizzled [R][64] bf16 tile: 8 bf16 at (row, chunk*8).
static __device__ __forceinline__ bf16x8 ld_frag(const uint8_t* lds, int row, int chunk) {
  return *(const bf16x8*)(lds + row * 128 + (((chunk) ^ (row & 7)) << 4));
}

// ---------------- f32 -> bf16 convert ----------------
__global__ __launch_bounds__(256) void cvtk(const float* __restrict__ in,
                                            uint16_t* __restrict__ out, int n4) {
  int i = blockIdx.x * 256 + threadIdx.x;
  if (i >= n4) return;
  float4 v = ((const float4*)in)[i];
  ushort4 o;
  o.x = f2b(v.x); o.y = f2b(v.y); o.z = f2b(v.z); o.w = f2b(v.w);
  ((ushort4*)out)[i] = o;
}

// ---------------- GEMM1: qkv = x @ w_in^T + b_in ----------------
// A: [4096][1024] bf16, W: [3072][1024] bf16. Tile 128x128, BK=64, 4 waves (2x2 of 64x64).
// Epilogue: e<1024 -> Q (B,H,S,DH); e<2048 -> K; else -> V transposed (B,H,DH,S).
__global__ __launch_bounds__(256) void gemm_qkv(const uint16_t* __restrict__ A,
                                                const uint16_t* __restrict__ W,
                                                const float* __restrict__ bias,
                                                uint16_t* __restrict__ Qb,
                                                uint16_t* __restrict__ Kb,
                                                uint16_t* __restrict__ Vt) {
  __shared__ uint8_t sm[32768];
  uint8_t* As = sm;
  uint8_t* Bs = sm + 16384;
  int t = threadIdx.x, l = t & 63, w = t >> 6;
  int m0 = blockIdx.y * 128, n0 = blockIdx.x * 128;
  int wr = (w >> 1) * 64, wc = (w & 1) * 64;
  const f32x4 fz = {0.f, 0.f, 0.f, 0.f};
  f32x4 acc[4][4];
#pragma unroll
  for (int i = 0; i < 4; ++i)
#pragma unroll
    for (int j = 0; j < 4; ++j) acc[i][j] = fz;

  for (int kt = 0; kt < 16; ++kt) {
    __syncthreads();
    stage64<4>(A + m0 * 1024 + kt * 64, 1024, As, t);
    stage64<4>(W + n0 * 1024 + kt * 64, 1024, Bs, t);
    __syncthreads();
#pragma unroll
    for (int ks = 0; ks < 2; ++ks) {
      bf16x8 a[4], b[4];
#pragma unroll
      for (int i = 0; i < 4; ++i) {
        a[i] = ld_frag(As, wr + i * 16 + (l & 15), ks * 4 + (l >> 4));
        b[i] = ld_frag(Bs, wc + i * 16 + (l & 15), ks * 4 + (l >> 4));
      }
#pragma unroll
      for (int i = 0; i < 4; ++i)
#pragma unroll
        for (int j = 0; j < 4; ++j)
          acc[i][j] = __builtin_amdgcn_mfma_f32_16x16x32_bf16(a[i], b[j], acc[i][j], 0, 0, 0);
    }
  }
#pragma unroll
  for (int j = 0; j < 4; ++j) {
    int e = n0 + wc + j * 16 + (l & 15);
    float bv = bias[e];
    int sec = e >> 10, ec = e & 1023, h = ec >> 6, dh = ec & 63;
#pragma unroll
    for (int i = 0; i < 4; ++i) {
      int mb = m0 + wr + i * 16 + ((l >> 4) << 2);
#pragma unroll
      for (int r = 0; r < 4; ++r) {
        int m = mb + r, bb = m >> 11, s = m & 2047;
        uint16_t hv = f2b(acc[i][j][r] + bv);
        if (sec == 0)      Qb[(((bb * 16 + h) * 2048 + s) << 6) + dh] = hv;
        else if (sec == 1) Kb[(((bb * 16 + h) * 2048 + s) << 6) + dh] = hv;
        else               Vt[(((bb * 16 + h) << 6) + dh) * 2048 + s] = hv;
      }
    }
  }
}

// ---------------- GEMM2: out = att @ w_out^T + b_out (f32 out) ----------------
__global__ __launch_bounds__(256) void gemm_out(const uint16_t* __restrict__ A,
                                                const uint16_t* __restrict__ W,
                                                const float* __restrict__ bias,
                                                float* __restrict__ out) {
  __shared__ uint8_t sm[32768];
  uint8_t* As = sm;
  uint8_t* Bs = sm + 16384;
  int t = threadIdx.x, l = t & 63, w = t >> 6;
  int m0 = blockIdx.y * 128, n0 = blockIdx.x * 128;
  int wr = (w >> 1) * 64, wc = (w & 1) * 64;
  const f32x4 fz = {0.f, 0.f, 0.f, 0.f};
  f32x4 acc[4][4];
#pragma unroll
  for (int i = 0; i < 4; ++i)
#pragma unroll
    for (int j = 0; j < 4; ++j) acc[i][j] = fz;

  for (int kt = 0; kt < 16; ++kt) {
    __syncthreads();
    stage64<4>(A + m0 * 1024 + kt * 64, 1024, As, t);
    stage64<4>(W + n0 * 1024 + kt * 64, 1024, Bs, t);
    __syncthreads();
#pragma unroll
    for (int ks = 0; ks < 2; ++ks) {
      bf16x8 a[4], b[4];
#pragma unroll
      for (int i = 0; i < 4; ++i) {
        a[i] = ld_frag(As, wr + i * 16 + (l & 15), ks * 4 + (l >> 4));
        b[i] = ld_frag(Bs, wc + i * 16 + (l & 15), ks * 4 + (l >> 4));
      }
#pragma unroll
      for (int i = 0; i < 4; ++i)
#pragma unroll
        for (int j = 0; j < 4; ++j)
          acc[i][j] = __builtin_amdgcn_mfma_f32_16x16x32_bf16(a[i], b[j], acc[i][j], 0, 0, 0);
    }
  }
#pragma unroll
  for (int j = 0; j < 4; ++j) {
    int e = n0 + wc + j * 16 + (l & 15);
    float bv = bias[e];
#pragma unroll
    for (int i = 0; i < 4; ++i) {
      int mb = m0 + wr + i * 16 + ((l >> 4) << 2);
#pragma unroll
      for (int r = 0; r < 4; ++r) {
        int m = mb + r;
        out[m * 1024 + e] = acc[i][j][r] + bv;
      }
    }
  }
}

// ---------------- Flash attention (causal), bf16 MFMA ----------------
// Grid: (qtile=S/64, bh=B*H). 4 waves/block, each wave owns 16 q-rows.
// Swapped QK^T: S^T = mfma(A=K_tile, B=Q) -> lane owns one q (=lane&15), kv spread
// over (lane>>4, reg, frag). Softmax reduce = local 16 + shfl_xor(16,32).
// P staged to per-wave swizzled LDS; PV: O = mfma(A=P, B=V^T-tile).
__global__ __launch_bounds__(256) void attn(const uint16_t* __restrict__ Qb,
                                            const uint16_t* __restrict__ Kb,
                                            const uint16_t* __restrict__ Vt,
                                            uint16_t* __restrict__ Ab,
                                            const int* __restrict__ maskp) {
  __shared__ uint8_t sm[24576];
  uint8_t* Ks = sm;          // K tile [64 kv][64 dh]
  uint8_t* Vs = sm + 8192;   // V^T tile [64 dh][64 kv]
  int t = threadIdx.x, l = t & 63, w = t >> 6;
  uint8_t* Ps = sm + 16384 + w * 2048;  // per-wave P tile [16 q][64 kv]
  int qt = blockIdx.x, bh = blockIdx.y;
  bool causal = (*maskp != 0);
  int nt = causal ? (qt + 1) : 32;
  int qbase = qt * 64 + w * 16;
  const float CS = 0.125f * 1.44269504088896340736f;  // 1/sqrt(64) * log2(e)

  // Hoist Q fragments (B-operand of swapped QK^T): Q[q=l&15][dh contiguous]
  bf16x8 qf[2];
#pragma unroll
  for (int ks = 0; ks < 2; ++ks)
    qf[ks] = *(const bf16x8*)(Qb + ((size_t)(bh * 2048 + qbase + (l & 15)) << 6) + ks * 32 + ((l >> 4) << 3));

  float mrun = -1e30f, lsum = 0.f;
  const f32x4 fz = {0.f, 0.f, 0.f, 0.f};
  f32x4 acco[4];
#pragma unroll
  for (int n = 0; n < 4; ++n) acco[n] = fz;

  for (int tt = 0; tt < nt; ++tt) {
    __syncthreads();
    stage64<2>(Kb + ((size_t)(bh * 2048 + tt * 64) << 6), 64, Ks, t);
    stage64<2>(Vt + (size_t)bh * 64 * 2048 + tt * 64, 2048, Vs, t);
    __syncthreads();

    // S^T tile: 4 frags along kv (M), N = q
    f32x4 sc[4];
#pragma unroll
    for (int f = 0; f < 4; ++f) sc[f] = fz;
#pragma unroll
    for (int f = 0; f < 4; ++f)
#pragma unroll
      for (int ks = 0; ks < 2; ++ks)
        sc[f] = __builtin_amdgcn_mfma_f32_16x16x32_bf16(
            ld_frag(Ks, f * 16 + (l & 15), ks * 4 + (l >> 4)), qf[ks], sc[f], 0, 0, 0);

    int q = qbase + (l & 15);
    float u[4][4];
    float tm = -1e30f;
#pragma unroll
    for (int f = 0; f < 4; ++f)
#pragma unroll
      for (int r = 0; r < 4; ++r) {
        int kv = tt * 64 + f * 16 + ((l >> 4) << 2) + r;
        float v = sc[f][r] * CS;
        if (causal && kv > q) v = -1e30f;
        u[f][r] = v;
        tm = fmaxf(tm, v);
      }
    tm = fmaxf(tm, __shfl_xor(tm, 16));
    tm = fmaxf(tm, __shfl_xor(tm, 32));
    float mnew = fmaxf(mrun, tm);
    float alpha = exp2f(mrun - mnew);
    mrun = mnew;

    float rs = 0.f;
#pragma unroll
    for (int f = 0; f < 4; ++f) {
      float p0 = exp2f(u[f][0] - mnew), p1 = exp2f(u[f][1] - mnew);
      float p2 = exp2f(u[f][2] - mnew), p3 = exp2f(u[f][3] - mnew);
      rs += (p0 + p1) + (p2 + p3);
      int kvl = f * 16 + ((l >> 4) << 2);       // 4-aligned run within an 8-elem chunk
      int row = l & 15;
      int byte = row * 128 + (((kvl >> 3) ^ (row & 7)) << 4) + (kvl & 7) * 2;
      uint2 pv;
      pv.x = pk2(p0, p1);
      pv.y = pk2(p2, p3);
      *(uint2*)(Ps + byte) = pv;
    }
    rs += __shfl_xor(rs, 16);
    rs += __shfl_xor(rs, 32);
    lsum = lsum * alpha + rs;

    asm volatile("s_waitcnt lgkmcnt(0)" ::: "memory");  // P writes visible before reads

    // Rescale O by alpha of its own q-rows (alpha lives at lane==q, q<16)
    float ao[4];
#pragma unroll
    for (int r = 0; r < 4; ++r) ao[r] = __shfl(alpha, ((l >> 4) << 2) + r);
#pragma unroll
    for (int n = 0; n < 4; ++n)
#pragma unroll
      for (int r = 0; r < 4; ++r) acco[n][r] *= ao[r];

#pragma unroll
    for (int ks = 0; ks < 2; ++ks) {
      bf16x8 ap = ld_frag(Ps, l & 15, ks * 4 + (l >> 4));
#pragma unroll
      for (int n = 0; n < 4; ++n) {
        bf16x8 bv = ld_frag(Vs, n * 16 + (l & 15), ks * 4 + (l >> 4));
        acco[n] = __builtin_amdgcn_mfma_f32_16x16x32_bf16(ap, bv, acco[n], 0, 0, 0);
      }
    }
  }

  float lo4[4];
#pragma unroll
  for (int r = 0; r < 4; ++r) lo4[r] = __shfl(lsum, ((l >> 4) << 2) + r);
  int bb = bh >> 4, h = bh & 15;
#pragma unroll
  for (int n = 0; n < 4; ++n)
#pragma unroll
    for (int r = 0; r < 4; ++r) {
      int qg = qbase + ((l >> 4) << 2) + r;
      float v = acco[n][r] / lo4[r];
      Ab[((size_t)(bb * 2048 + qg) << 10) + h * 64 + n * 16 + (l & 15)] = f2b(v);
    }
}

extern "C" void kernel_launch(void* const* d_in, const int* in_sizes, int n_in,
                              void* d_out, int out_size, void* d_ws, size_t ws_size,
                              hipStream_t stream) {
  const float* x     = (const float*)d_in[0];
  const float* w_in  = (const float*)d_in[1];
  const float* b_in  = (const float*)d_in[2];
  const float* w_out = (const float*)d_in[3];
  const float* b_out = (const float*)d_in[4];
  const int*   mask  = (const int*)d_in[5];
  float* out = (float*)d_out;

  uint8_t* ws = (uint8_t*)d_ws;
  uint16_t* xb  = (uint16_t*)(ws);                  // 8 MB  x bf16 [4096][1024]
  uint16_t* wib = (uint16_t*)(ws + (8u << 20));     // 6 MB  w_in bf16 [3072][1024]
  uint16_t* wob = (uint16_t*)(ws + (14u << 20));    // 2 MB  w_out bf16 [1024][1024]
  uint16_t* Qb  = (uint16_t*)(ws + (16u << 20));    // 8 MB  (B,H,S,DH)
  uint16_t* Kb  = (uint16_t*)(ws + (24u << 20));    // 8 MB  (B,H,S,DH)
  uint16_t* Vt  = (uint16_t*)(ws + (32u << 20));    // 8 MB  (B,H,DH,S)
  uint16_t* Ab  = (uint16_t*)(ws + (40u << 20));    // 8 MB  att (B,S,D) bf16

  cvtk<<<4096, 256, 0, stream>>>(x, xb, 4096 * 1024 / 4);
  cvtk<<<3072, 256, 0, stream>>>(w_in, wib, 3072 * 1024 / 4);
  cvtk<<<1024, 256, 0, stream>>>(w_out, wob, 1024 * 1024 / 4);
  gemm_qkv<<<dim3(24, 32), 256, 0, stream>>>(xb, wib, b_in, Qb, Kb, Vt);
  attn<<<dim3(32, 32), 256, 0, stream>>>(Qb, Kb, Vt, Ab, mask);
  gemm_out<<<dim3(8, 32), 256, 0, stream>>>(Ab, wob, b_out, out);
}

// Round 3
// 179.505 us; speedup vs baseline: 1.0574x; 1.0574x over previous
//
#include <hip/hip_runtime.h>
#include <hip/hip_bf16.h>
#include <stdint.h>

// B=2, S=2048, D=1024, H=16, DH=64. Causal self-attention block, bf16 MFMA pipeline.

typedef __attribute__((ext_vector_type(8))) short bf16x8;   // 8 bf16 = 16B (A/B frag)
typedef __attribute__((ext_vector_type(4))) float f32x4;    // C/D frag 16x16
typedef __attribute__((ext_vector_type(16))) float f32x16;  // C/D frag 32x32
typedef __attribute__((ext_vector_type(4))) unsigned int u32x4;
typedef __attribute__((ext_vector_type(2))) unsigned int u32x2;

typedef const __attribute__((address_space(1))) uint32_t* gp1_t;
typedef __attribute__((address_space(3))) uint32_t* lp3_t;

static __device__ __forceinline__ uint16_t f2b(float x) {
  __hip_bfloat16 h = __float2bfloat16(x);
  return *reinterpret_cast<uint16_t*>(&h);
}

// v_cvt_pk_bf16_f32: dst.lo = bf16(lo), dst.hi = bf16(hi)
static __device__ __forceinline__ uint32_t cvtpk(float lo, float hi) {
  uint32_t r;
  asm("v_cvt_pk_bf16_f32 %0, %1, %2" : "=v"(r) : "v"(lo), "v"(hi));
  return r;
}

// Stage R rows x 64 bf16 (128B = 8 chunks of 16B) tile into LDS.
// LDS dest linear (global_load_lds requirement); XOR swizzle (chunk ^= row&7)
// applied by pre-swizzling the per-lane GLOBAL source address.
template <int ISSUES>
static __device__ __forceinline__ void stage64(const uint16_t* __restrict__ g, int gstride,
                                               uint8_t* lds, int t) {
#pragma unroll
  for (int i = 0; i < ISSUES; ++i) {
    int p = i * 256 + t;          // 16B-chunk index
    int row = p >> 3, c = p & 7;
    const uint16_t* src = g + row * gstride + ((c ^ (row & 7)) << 3);
    __builtin_amdgcn_global_load_lds((gp1_t)src, (lp3_t)(lds + (p & ~63) * 16), 16, 0, 0);
  }
}

// Read a 16B fragment from a swizzled [R][64] bf16 tile: 8 bf16 at (row, chunk*8).
static __device__ __forceinline__ bf16x8 ld_frag(const uint8_t* lds, int row, int chunk) {
  return *(const bf16x8*)(lds + row * 128 + (((chunk) ^ (row & 7)) << 4));
}

// PV B-operand with permuted-k slots: element j<4 from chunk c0 (bytes 8*hi..),
// j>=4 from chunk c0+1 (bytes 8*hi..). kv(j) = c0*8 + 8*(j>>2) + 4*hi + (j&3).
static __device__ __forceinline__ bf16x8 ld_pv_b(const uint8_t* lds, int row, int c0, int hi) {
  const uint8_t* base = lds + row * 128 + hi * 8;
  u32x2 lo = *(const u32x2*)(base + (((c0)     ^ (row & 7)) << 4));
  u32x2 up = *(const u32x2*)(base + (((c0 + 1) ^ (row & 7)) << 4));
  u32x4 wv = {lo[0], lo[1], up[0], up[1]};
  return __builtin_bit_cast(bf16x8, wv);
}

// ---------------- f32 -> bf16 convert ----------------
__global__ __launch_bounds__(256) void cvtk(const float* __restrict__ in,
                                            uint16_t* __restrict__ out, int n4) {
  int i = blockIdx.x * 256 + threadIdx.x;
  if (i >= n4) return;
  float4 v = ((const float4*)in)[i];
  ushort4 o;
  o.x = f2b(v.x); o.y = f2b(v.y); o.z = f2b(v.z); o.w = f2b(v.w);
  ((ushort4*)out)[i] = o;
}

// ---------------- GEMM1: qkv = x @ w_in^T + b_in ----------------
__global__ __launch_bounds__(256) void gemm_qkv(const uint16_t* __restrict__ A,
                                                const uint16_t* __restrict__ W,
                                                const float* __restrict__ bias,
                                                uint16_t* __restrict__ Qb,
                                                uint16_t* __restrict__ Kb,
                                                uint16_t* __restrict__ Vt) {
  __shared__ uint8_t sm[32768];
  uint8_t* As = sm;
  uint8_t* Bs = sm + 16384;
  int t = threadIdx.x, l = t & 63, w = t >> 6;
  int m0 = blockIdx.y * 128, n0 = blockIdx.x * 128;
  int wr = (w >> 1) * 64, wc = (w & 1) * 64;
  const f32x4 fz = {0.f, 0.f, 0.f, 0.f};
  f32x4 acc[4][4];
#pragma unroll
  for (int i = 0; i < 4; ++i)
#pragma unroll
    for (int j = 0; j < 4; ++j) acc[i][j] = fz;

  for (int kt = 0; kt < 16; ++kt) {
    __syncthreads();
    stage64<4>(A + m0 * 1024 + kt * 64, 1024, As, t);
    stage64<4>(W + n0 * 1024 + kt * 64, 1024, Bs, t);
    __syncthreads();
#pragma unroll
    for (int ks = 0; ks < 2; ++ks) {
      bf16x8 a[4], b[4];
#pragma unroll
      for (int i = 0; i < 4; ++i) {
        a[i] = ld_frag(As, wr + i * 16 + (l & 15), ks * 4 + (l >> 4));
        b[i] = ld_frag(Bs, wc + i * 16 + (l & 15), ks * 4 + (l >> 4));
      }
#pragma unroll
      for (int i = 0; i < 4; ++i)
#pragma unroll
        for (int j = 0; j < 4; ++j)
          acc[i][j] = __builtin_amdgcn_mfma_f32_16x16x32_bf16(a[i], b[j], acc[i][j], 0, 0, 0);
    }
  }
#pragma unroll
  for (int j = 0; j < 4; ++j) {
    int e = n0 + wc + j * 16 + (l & 15);
    float bv = bias[e];
    int sec = e >> 10, ec = e & 1023, h = ec >> 6, dh = ec & 63;
#pragma unroll
    for (int i = 0; i < 4; ++i) {
      int mb = m0 + wr + i * 16 + ((l >> 4) << 2);
#pragma unroll
      for (int r = 0; r < 4; ++r) {
        int m = mb + r, bb = m >> 11, s = m & 2047;
        uint16_t hv = f2b(acc[i][j][r] + bv);
        if (sec == 0)      Qb[(((bb * 16 + h) * 2048 + s) << 6) + dh] = hv;
        else if (sec == 1) Kb[(((bb * 16 + h) * 2048 + s) << 6) + dh] = hv;
        else               Vt[(((bb * 16 + h) << 6) + dh) * 2048 + s] = hv;
      }
    }
  }
}

// ---------------- GEMM2: out = att @ w_out^T + b_out (f32 out) ----------------
__global__ __launch_bounds__(256) void gemm_out(const uint16_t* __restrict__ A,
                                                const uint16_t* __restrict__ W,
                                                const float* __restrict__ bias,
                                                float* __restrict__ out) {
  __shared__ uint8_t sm[32768];
  uint8_t* As = sm;
  uint8_t* Bs = sm + 16384;
  int t = threadIdx.x, l = t & 63, w = t >> 6;
  int m0 = blockIdx.y * 128, n0 = blockIdx.x * 128;
  int wr = (w >> 1) * 64, wc = (w & 1) * 64;
  const f32x4 fz = {0.f, 0.f, 0.f, 0.f};
  f32x4 acc[4][4];
#pragma unroll
  for (int i = 0; i < 4; ++i)
#pragma unroll
    for (int j = 0; j < 4; ++j) acc[i][j] = fz;

  for (int kt = 0; kt < 16; ++kt) {
    __syncthreads();
    stage64<4>(A + m0 * 1024 + kt * 64, 1024, As, t);
    stage64<4>(W + n0 * 1024 + kt * 64, 1024, Bs, t);
    __syncthreads();
#pragma unroll
    for (int ks = 0; ks < 2; ++ks) {
      bf16x8 a[4], b[4];
#pragma unroll
      for (int i = 0; i < 4; ++i) {
        a[i] = ld_frag(As, wr + i * 16 + (l & 15), ks * 4 + (l >> 4));
        b[i] = ld_frag(Bs, wc + i * 16 + (l & 15), ks * 4 + (l >> 4));
      }
#pragma unroll
      for (int i = 0; i < 4; ++i)
#pragma unroll
        for (int j = 0; j < 4; ++j)
          acc[i][j] = __builtin_amdgcn_mfma_f32_16x16x32_bf16(a[i], b[j], acc[i][j], 0, 0, 0);
    }
  }
#pragma unroll
  for (int j = 0; j < 4; ++j) {
    int e = n0 + wc + j * 16 + (l & 15);
    float bv = bias[e];
#pragma unroll
    for (int i = 0; i < 4; ++i) {
      int mb = m0 + wr + i * 16 + ((l >> 4) << 2);
#pragma unroll
      for (int r = 0; r < 4; ++r) {
        int m = mb + r;
        out[m * 1024 + e] = acc[i][j][r] + bv;
      }
    }
  }
}

// ---------------- Flash attention (causal), 32x32 MFMA, in-register P ----------------
// Grid: (16 q-supertiles of 128 rows [reversed: heavy first], 32 bh). 4 waves/block,
// each wave owns 32 q rows. Swapped QK^T: sc = mfma32(A=K, B=Q) -> lane owns q=lane&31,
// kv rows = (r&3)+8*(r>>2)+4*(lane>>5) per 32-row frag (guide §B verified mapping).
// PV uses a permuted k-slot bijection so the A-operand (P) is fully lane-local:
//   kv(ks,hi,j) = 32*(ks>>1) + 16*(ks&1) + 8*(j>>2) + 4*hi + (j&3)
//   => af[ks][j] = p[ks>>1][(ks&1)*8 + j]  (contiguous, zero cross-lane ops)
//   B-side reads V^T with the same bijection via two b64 LDS reads per frag.
__global__ __launch_bounds__(256) void attn(const uint16_t* __restrict__ Qb,
                                            const uint16_t* __restrict__ Kb,
                                            const uint16_t* __restrict__ Vt,
                                            uint16_t* __restrict__ Ab,
                                            const int* __restrict__ maskp) {
  __shared__ uint8_t sm[16384];
  uint8_t* Ks = sm;          // K tile [64 kv][64 dh] (swizzled)
  uint8_t* Vs = sm + 8192;   // V^T tile [64 dh][64 kv] (swizzled)
  int t = threadIdx.x, l = t & 63, w = t >> 6;
  int hi = l >> 5, ql = l & 31;
  int qt = 15 - (int)blockIdx.x;    // heavy blocks dispatched first
  int bh = blockIdx.y;
  bool causal = (*maskp != 0);
  int nt = causal ? 2 * (qt + 1) : 32;
  int q0 = qt * 128 + w * 32;       // wave's q base
  int q = q0 + ql;                  // this lane's q row (for QK output)
  const float CS = 0.125f * 1.44269504088896340736f;  // 1/sqrt(64) * log2(e)

  // Q fragments (B-operand): Q[q][dh = ks*16 + hi*8 + j]
  bf16x8 qf[4];
#pragma unroll
  for (int ks = 0; ks < 4; ++ks)
    qf[ks] = *(const bf16x8*)(Qb + (((size_t)(bh * 2048 + q)) << 6) + ks * 16 + hi * 8);

  f32x16 acco[2];
#pragma unroll
  for (int r = 0; r < 16; ++r) { acco[0][r] = 0.f; acco[1][r] = 0.f; }
  float mrun = -1e30f, lsum = 0.f;

  for (int tt = 0; tt < nt; ++tt) {
    __syncthreads();
    stage64<2>(Kb + (((size_t)(bh * 2048 + tt * 64)) << 6), 64, Ks, t);
    stage64<2>(Vt + (size_t)bh * 131072 + tt * 64, 2048, Vs, t);
    __syncthreads();

    // QK^T: sc[f][r] = S[kv = tt*64 + f*32 + crow(r,hi)][q]
    f32x16 sc[2];
#pragma unroll
    for (int r = 0; r < 16; ++r) { sc[0][r] = 0.f; sc[1][r] = 0.f; }
    __builtin_amdgcn_s_setprio(1);
#pragma unroll
    for (int f = 0; f < 2; ++f)
#pragma unroll
      for (int ks = 0; ks < 4; ++ks)
        sc[f] = __builtin_amdgcn_mfma_f32_32x32x16_bf16(
            ld_frag(Ks, f * 32 + ql, ks * 2 + hi), qf[ks], sc[f], 0, 0, 0);
    __builtin_amdgcn_s_setprio(0);

    // scale + causal mask (log2 domain), running max
    float p[2][16];
    float tm = -1e30f;
    bool nomask = (!causal) || (tt * 64 + 63 <= q0);
#pragma unroll
    for (int f = 0; f < 2; ++f)
#pragma unroll
      for (int r = 0; r < 16; ++r) {
        float v = sc[f][r] * CS;
        if (!nomask) {
          int kv = tt * 64 + f * 32 + ((r & 3) + 8 * (r >> 2) + 4 * hi);
          v = (kv <= q) ? v : -1e30f;
        }
        p[f][r] = v;
        tm = fmaxf(tm, v);
      }
    tm = fmaxf(tm, __shfl_xor(tm, 32));

    // defer-max (T13): skip rescale when max growth small
    bool defer = __all(tm <= mrun + 8.0f);
    if (!defer) {
      float mnew = fmaxf(mrun, tm);
      float alpha = exp2f(mrun - mnew);
      mrun = mnew;
      lsum *= alpha;
#pragma unroll
      for (int r = 0; r < 16; ++r) {
        float av = __shfl(alpha, (r & 3) + 8 * (r >> 2) + 4 * hi);
        acco[0][r] *= av;
        acco[1][r] *= av;
      }
    }
    float rs = 0.f;
#pragma unroll
    for (int f = 0; f < 2; ++f)
#pragma unroll
      for (int r = 0; r < 16; ++r) {
        float e = exp2f(p[f][r] - mrun);
        p[f][r] = e;
        rs += e;
      }
    rs += __shfl_xor(rs, 32);
    lsum += rs;

    // PV with lane-local P fragments (zero-shuffle):
    __builtin_amdgcn_s_setprio(1);
#pragma unroll
    for (int ks = 0; ks < 4; ++ks) {
      int f = ks >> 1, a8 = (ks & 1) * 8;
      u32x4 wv = {cvtpk(p[f][a8 + 0], p[f][a8 + 1]),
                  cvtpk(p[f][a8 + 2], p[f][a8 + 3]),
                  cvtpk(p[f][a8 + 4], p[f][a8 + 5]),
                  cvtpk(p[f][a8 + 6], p[f][a8 + 7])};
      bf16x8 af = __builtin_bit_cast(bf16x8, wv);
      int c0 = 4 * f + 2 * (ks & 1);
#pragma unroll
      for (int n = 0; n < 2; ++n)
        acco[n] = __builtin_amdgcn_mfma_f32_32x32x16_bf16(
            af, ld_pv_b(Vs, n * 32 + ql, c0, hi), acco[n], 0, 0, 0);
    }
    __builtin_amdgcn_s_setprio(0);
  }

  // epilogue: O[q = q0 + crow(r,hi)][dh = n*32 + ql] / lsum[q]
  int bb = bh >> 4, h = bh & 15;
#pragma unroll
  for (int r = 0; r < 16; ++r) {
    int crow = (r & 3) + 8 * (r >> 2) + 4 * hi;
    float ls = __shfl(lsum, crow);
    float inv = 1.0f / ls;
    int qg = q0 + crow;
#pragma unroll
    for (int n = 0; n < 2; ++n)
      Ab[(((size_t)(bb * 2048 + qg)) << 10) + h * 64 + n * 32 + ql] = f2b(acco[n][r] * inv);
  }
}

extern "C" void kernel_launch(void* const* d_in, const int* in_sizes, int n_in,
                              void* d_out, int out_size, void* d_ws, size_t ws_size,
                              hipStream_t stream) {
  const float* x     = (const float*)d_in[0];
  const float* w_in  = (const float*)d_in[1];
  const float* b_in  = (const float*)d_in[2];
  const float* w_out = (const float*)d_in[3];
  const float* b_out = (const float*)d_in[4];
  const int*   mask  = (const int*)d_in[5];
  float* out = (float*)d_out;

  uint8_t* ws = (uint8_t*)d_ws;
  uint16_t* xb  = (uint16_t*)(ws);                  // 8 MB  x bf16 [4096][1024]
  uint16_t* wib = (uint16_t*)(ws + (8u << 20));     // 6 MB  w_in bf16 [3072][1024]
  uint16_t* wob = (uint16_t*)(ws + (14u << 20));    // 2 MB  w_out bf16 [1024][1024]
  uint16_t* Qb  = (uint16_t*)(ws + (16u << 20));    // 8 MB  (B,H,S,DH)
  uint16_t* Kb  = (uint16_t*)(ws + (24u << 20));    // 8 MB  (B,H,S,DH)
  uint16_t* Vt  = (uint16_t*)(ws + (32u << 20));    // 8 MB  (B,H,DH,S)
  uint16_t* Ab  = (uint16_t*)(ws + (40u << 20));    // 8 MB  att (B,S,D) bf16

  cvtk<<<4096, 256, 0, stream>>>(x, xb, 4096 * 1024 / 4);
  cvtk<<<3072, 256, 0, stream>>>(w_in, wib, 3072 * 1024 / 4);
  cvtk<<<1024, 256, 0, stream>>>(w_out, wob, 1024 * 1024 / 4);
  gemm_qkv<<<dim3(24, 32), 256, 0, stream>>>(xb, wib, b_in, Qb, Kb, Vt);
  attn<<<dim3(16, 32), 256, 0, stream>>>(Qb, Kb, Vt, Ab, mask);
  gemm_out<<<dim3(8, 32), 256, 0, stream>>>(Ab, wob, b_out, out);
}